// Round 7
// baseline (1290.649 us; speedup 1.0000x reference)
//
#include <hip/hip_runtime.h>
#include <cstdint>
#include <cstddef>

#define BATCH   65536
#define RANK_K  32769   // sorted_desc[32768] == 32769-th largest (1-indexed)

// ============ big GEMM (layers 1&2): C = relu((A*rowmask) @ B + bias) + per-row sumsq partials ============
// Round-7: exact r2 structure (validated 623 us GEMM1) with ONE change: staggered Bs column-block
// offsets (+4 words for tc>=8) so B-fragment ds_read_b128 addresses cover all 8 bank-quads
// (2-way = free) instead of only even quads (4-way = 1.58x). Thread<->column ownership is
// unchanged, so every FMA chain / rowsum chain is bit-identical to the validated kernel.
template<bool MASKED>
__global__ __launch_bounds__(256, 2)
void gemm_relu_norm(const float* __restrict__ A, const float* __restrict__ B,
                    const float* __restrict__ bias,
                    const float* __restrict__ prevNorms, const unsigned* __restrict__ thrKey,
                    float* __restrict__ C, float* __restrict__ normPart,
                    const int N, const int K)
{
    __shared__ float As[16][260];   // [k][row], padded
    __shared__ float Bs[16][136];   // [k][col-staggered], padded
    __shared__ float red[256][17];  // row-norm partial reduction (separate, as in r2)

    const int t    = threadIdx.x;
    const int tr   = t >> 4;          // 0..15 row group (16 rows each)
    const int tc   = t & 15;          // 0..15 col group (8 cols each)
    const int row0 = blockIdx.x * 256;
    const int col0 = blockIdx.y * 128;

    // A-load: thread t loads row (row0+t), 16 consecutive k per tile
    const float* Aptr = A + (size_t)(row0 + t) * K;
    // B-load: 16 k-rows x 128 cols; thread: k=t>>4, global cols (t&15)*8..+7
    const int bk = t >> 4;
    const int bgc = (t & 15) * 8;                       // natural global column offset
    const int bo  = bgc + (((t & 15) >> 3) << 2);       // staggered LDS word offset
    const float* Bptr = B + (size_t)bk * N + col0 + bgc;
    const int readBo = tc * 8 + ((tc >> 3) << 2);       // this thread's staggered read offset

    float scale = 1.0f;
    if (MASKED) scale = (__float_as_uint(prevNorms[row0 + t]) > thrKey[0]) ? 1.0f : 0.0f;

    float acc[16][8];
    #pragma unroll
    for (int i = 0; i < 16; ++i)
        #pragma unroll
        for (int j = 0; j < 8; ++j) acc[i][j] = 0.0f;

    for (int k0 = 0; k0 < K; k0 += 16) {
        float4 a0 = *(const float4*)(Aptr + k0);
        float4 a1 = *(const float4*)(Aptr + k0 + 4);
        float4 a2 = *(const float4*)(Aptr + k0 + 8);
        float4 a3 = *(const float4*)(Aptr + k0 + 12);
        float4 b0 = *(const float4*)(Bptr + (size_t)k0 * N);
        float4 b1 = *(const float4*)(Bptr + (size_t)k0 * N + 4);
        if (MASKED) {
            a0.x *= scale; a0.y *= scale; a0.z *= scale; a0.w *= scale;
            a1.x *= scale; a1.y *= scale; a1.z *= scale; a1.w *= scale;
            a2.x *= scale; a2.y *= scale; a2.z *= scale; a2.w *= scale;
            a3.x *= scale; a3.y *= scale; a3.z *= scale; a3.w *= scale;
        }
        As[ 0][t] = a0.x; As[ 1][t] = a0.y; As[ 2][t] = a0.z; As[ 3][t] = a0.w;
        As[ 4][t] = a1.x; As[ 5][t] = a1.y; As[ 6][t] = a1.z; As[ 7][t] = a1.w;
        As[ 8][t] = a2.x; As[ 9][t] = a2.y; As[10][t] = a2.z; As[11][t] = a2.w;
        As[12][t] = a3.x; As[13][t] = a3.y; As[14][t] = a3.z; As[15][t] = a3.w;
        *(float4*)&Bs[bk][bo]     = b0;
        *(float4*)&Bs[bk][bo + 4] = b1;
        __syncthreads();
        #pragma unroll
        for (int kk = 0; kk < 16; ++kk) {
            float a_[16], b_[8];
            *(float4*)&a_[0]  = *(const float4*)&As[kk][tr*16];
            *(float4*)&a_[4]  = *(const float4*)&As[kk][tr*16 + 4];
            *(float4*)&a_[8]  = *(const float4*)&As[kk][tr*16 + 8];
            *(float4*)&a_[12] = *(const float4*)&As[kk][tr*16 + 12];
            *(float4*)&b_[0]  = *(const float4*)&Bs[kk][readBo];
            *(float4*)&b_[4]  = *(const float4*)&Bs[kk][readBo + 4];
            #pragma unroll
            for (int i = 0; i < 16; ++i)
                #pragma unroll
                for (int j = 0; j < 8; ++j)
                    acc[i][j] = fmaf(a_[i], b_[j], acc[i][j]);
        }
        __syncthreads();
    }

    float bv[8];
    #pragma unroll
    for (int j = 0; j < 8; ++j) bv[j] = bias[col0 + tc*8 + j];

    float rowsum[16];
    #pragma unroll
    for (int i = 0; i < 16; ++i) {
        float s = 0.0f;
        #pragma unroll
        for (int j = 0; j < 8; ++j) {
            float v = fmaxf(acc[i][j] + bv[j], 0.0f);   // dot, +bias, relu (matches ref)
            acc[i][j] = v;
            s = fmaf(v, v, s);
        }
        rowsum[i] = s;
    }

    #pragma unroll
    for (int i = 0; i < 16; ++i) {
        const size_t row = (size_t)(row0 + tr*16 + i);
        *(float4*)&C[row * N + col0 + tc*8]     = *(float4*)&acc[i][0];
        *(float4*)&C[row * N + col0 + tc*8 + 4] = *(float4*)&acc[i][4];
    }

    #pragma unroll
    for (int i = 0; i < 16; ++i) red[tr*16 + i][tc] = rowsum[i];
    __syncthreads();
    {
        float s = 0.0f;
        #pragma unroll
        for (int x = 0; x < 16; ++x) s += red[t][x];    // fixed order -> deterministic
        normPart[(size_t)blockIdx.y * BATCH + row0 + t] = s;
    }
}

// ============ deterministic partial-sum -> norm (sqrt in double = correctly-rounded fp32 sqrt) ============
__global__ __launch_bounds__(256)
void reduce_norms_kernel(const float* __restrict__ part, float* __restrict__ norms, const int nPart)
{
    const int i = blockIdx.x * 256 + threadIdx.x;
    float s = 0.0f;
    for (int p = 0; p < nPart; ++p) s += part[(size_t)p * BATCH + i];
    norms[i] = (float)sqrt((double)s);
}

// ============ exact 32769-th-largest: multi-level 4096-bin histogram (single WG) ============
// Exact for any distribution incl. 32767-multiplicity ties (masked rows are identical ->
// identical norms). <=3 levels: width shrinks ~4096x per level until bin width == 1 ulp.
__global__ __launch_bounds__(1024)
void select_kernel(const float* __restrict__ norms, unsigned* __restrict__ thrOut)
{
    __shared__ unsigned hist[4096];
    __shared__ unsigned ssum[1024];
    __shared__ unsigned wmin[16], wmax[16], gsum[16];
    __shared__ unsigned sLo, sHi;
    __shared__ int      sRk;

    const int t = threadIdx.x;
    unsigned key[64];
    const float4* n4p = (const float4*)norms;
    #pragma unroll
    for (int i = 0; i < 16; ++i) {
        float4 v = n4p[i * 1024 + t];
        key[i*4+0] = __float_as_uint(v.x);
        key[i*4+1] = __float_as_uint(v.y);
        key[i*4+2] = __float_as_uint(v.z);
        key[i*4+3] = __float_as_uint(v.w);          // nonneg floats -> monotone uint order
    }

    unsigned mn = key[0], mx = key[0];
    #pragma unroll
    for (int i = 1; i < 64; ++i) { mn = min(mn, key[i]); mx = max(mx, key[i]); }
    #pragma unroll
    for (int off = 32; off > 0; off >>= 1) {
        mn = min(mn, (unsigned)__shfl_down((int)mn, off, 64));
        mx = max(mx, (unsigned)__shfl_down((int)mx, off, 64));
    }
    if ((t & 63) == 0) { wmin[t >> 6] = mn; wmax[t >> 6] = mx; }
    __syncthreads();
    if (t == 0) {
        unsigned m0 = wmin[0], m1 = wmax[0];
        for (int q = 1; q < 16; ++q) { m0 = min(m0, wmin[q]); m1 = max(m1, wmax[q]); }
        sLo = m0; sHi = m1; sRk = RANK_K;
    }
    __syncthreads();

    // invariant: answer V in [sLo, sHi]; sRk = RANK_K - count(key > sHi)
    while (true) {
        const unsigned lo = sLo, hi = sHi;
        const int rk = sRk;
        if (lo == hi) break;                         // uniform (shared state after barrier)
        const unsigned width = hi - lo;
        int sh = 0;
        while ((width >> sh) >= 4096u) ++sh;         // uniform scalar

        hist[t] = 0; hist[t+1024] = 0; hist[t+2048] = 0; hist[t+3072] = 0;
        __syncthreads();
        #pragma unroll
        for (int i = 0; i < 64; ++i) {
            const unsigned k = key[i];
            if (k >= lo && k <= hi) atomicAdd(&hist[(k - lo) >> sh], 1u);
        }
        __syncthreads();
        ssum[t] = hist[4*t] + hist[4*t+1] + hist[4*t+2] + hist[4*t+3];
        __syncthreads();
        if (t < 16) {
            unsigned g = 0;
            for (int q = 0; q < 64; ++q) g += ssum[t*64 + q];
            gsum[t] = g;
        }
        __syncthreads();
        if (t == 0) {
            int cum = 0; int g, q, b;
            for (g = 15; g >= 0; --g) { if (cum + (int)gsum[g] >= rk) break; cum += (int)gsum[g]; }
            for (q = g*64 + 63; q >= g*64; --q) { if (cum + (int)ssum[q] >= rk) break; cum += (int)ssum[q]; }
            for (b = q*4 + 3; b >= q*4; --b) { if (cum + (int)hist[b] >= rk) break; cum += (int)hist[b]; }
            sRk = rk - cum;
            const unsigned newLo = lo + ((unsigned)b << sh);
            sLo = newLo;
            sHi = (sh == 0) ? newLo : min(hi, newLo + (1u << sh) - 1u);
        }
        __syncthreads();
    }
    if (t == 0) thrOut[0] = sLo;
}

// ============ layer 3: h3 = relu((h2*m2) @ W3[256x10] + b3), full row norms ============
// Round-7: one row per thread (reads h2 once, not 4x). Per-output dot-product expression and
// the (3,3,3,1) + ((g0+g1)+g2)+g3 norm reduction reproduced verbatim -> identical values.
__global__ __launch_bounds__(256)
void layer3_kernel(const float* __restrict__ h2, const float* __restrict__ W3,
                   const float* __restrict__ b3,
                   const float* __restrict__ n2, const unsigned* __restrict__ thr2,
                   float* __restrict__ h3, float* __restrict__ norms3)
{
    __shared__ float wT[10][260];   // transposed W3, broadcast-friendly

    const int t   = threadIdx.x;
    const int row = blockIdx.x * 256 + t;

    for (int e = t; e < 2560; e += 256) wT[e % 10][e / 10] = W3[e];
    __syncthreads();

    const float m = (__float_as_uint(n2[row]) > thr2[0]) ? 1.0f : 0.0f;
    const float* hrow = h2 + (size_t)row * 256;

    float acc[10];
    #pragma unroll
    for (int j = 0; j < 10; ++j) acc[j] = 0.0f;

    for (int k = 0; k < 256; k += 4) {
        float4 v = *(const float4*)(hrow + k);
        v.x *= m; v.y *= m; v.z *= m; v.w *= m;
        #pragma unroll
        for (int j = 0; j < 10; ++j) {
            float4 w = *(const float4*)&wT[j][k];
            acc[j] += v.x*w.x + v.y*w.y + v.z*w.z + v.w*w.w;   // same expression as validated kernel
        }
    }

    float hv[10];
    #pragma unroll
    for (int j = 0; j < 10; ++j) hv[j] = fmaxf(acc[j] + b3[j], 0.0f);
    #pragma unroll
    for (int j = 0; j < 10; ++j) h3[(size_t)row * 10 + j] = hv[j];

    float ss0 = 0.0f, ss1 = 0.0f, ss2 = 0.0f, ss3 = 0.0f;
    ss0 += hv[0]*hv[0]; ss0 += hv[1]*hv[1]; ss0 += hv[2]*hv[2];
    ss1 += hv[3]*hv[3]; ss1 += hv[4]*hv[4]; ss1 += hv[5]*hv[5];
    ss2 += hv[6]*hv[6]; ss2 += hv[7]*hv[7]; ss2 += hv[8]*hv[8];
    ss3 += hv[9]*hv[9];
    const float tot = ((ss0 + ss1) + ss2) + ss3;               // same association as validated kernel
    norms3[row] = (float)sqrt((double)tot);
}

// ============ layer 4: h4 = (h3*m3) @ W4[10x10] + b4 (no relu), norms ============
__global__ __launch_bounds__(256)
void layer4_kernel(const float* __restrict__ h3, const float* __restrict__ W4,
                   const float* __restrict__ b4,
                   const float* __restrict__ n3, const unsigned* __restrict__ thr3,
                   float* __restrict__ h4, float* __restrict__ norms4)
{
    __shared__ float w[100];
    __shared__ float bb[10];
    const int t = threadIdx.x;
    if (t < 100) w[t] = W4[t];
    if (t < 10)  bb[t] = b4[t];
    __syncthreads();

    const int row = blockIdx.x * 256 + t;
    const float m = (__float_as_uint(n3[row]) > thr3[0]) ? 1.0f : 0.0f;
    const float* hr = h3 + (size_t)row * 10;
    float v[10];
    #pragma unroll
    for (int k = 0; k < 10; ++k) v[k] = hr[k] * m;

    float s = 0.0f;
    #pragma unroll
    for (int j = 0; j < 10; ++j) {
        float a = 0.0f;
        #pragma unroll
        for (int k = 0; k < 10; ++k) a = fmaf(v[k], w[k*10 + j], a);
        a += bb[j];
        h4[(size_t)row * 10 + j] = a;
        s = fmaf(a, a, s);
    }
    norms4[row] = (float)sqrt((double)s);
}

// ============ final: out = softmax(h4 * m4) ============
__global__ __launch_bounds__(256)
void softmax_kernel(const float* __restrict__ h4,
                    const float* __restrict__ n4, const unsigned* __restrict__ thr4,
                    float* __restrict__ out)
{
    const int t   = threadIdx.x;
    const int row = blockIdx.x * 256 + t;
    const float m = (__float_as_uint(n4[row]) > thr4[0]) ? 1.0f : 0.0f;
    const float* hr = h4 + (size_t)row * 10;
    float v[10];
    #pragma unroll
    for (int k = 0; k < 10; ++k) v[k] = hr[k] * m;
    float mx = v[0];
    #pragma unroll
    for (int k = 1; k < 10; ++k) mx = fmaxf(mx, v[k]);
    float e[10];
    float s = 0.0f;
    #pragma unroll
    for (int k = 0; k < 10; ++k) { e[k] = expf(v[k] - mx); s += e[k]; }
    const float inv = 1.0f / s;
    #pragma unroll
    for (int k = 0; k < 10; ++k) out[(size_t)row * 10 + k] = e[k] * inv;
}

// ============ materialize all four masks into d_out ============
__global__ __launch_bounds__(256)
void masks_kernel(const float* __restrict__ n1, const float* __restrict__ n2,
                  const float* __restrict__ n3, const float* __restrict__ n4,
                  const unsigned* __restrict__ thr,
                  float* __restrict__ m1, float* __restrict__ m2,
                  float* __restrict__ m3, float* __restrict__ m4)
{
    const int i = blockIdx.x * 256 + threadIdx.x;
    m1[i] = (__float_as_uint(n1[i]) > thr[0]) ? 1.0f : 0.0f;
    m2[i] = (__float_as_uint(n2[i]) > thr[1]) ? 1.0f : 0.0f;
    m3[i] = (__float_as_uint(n3[i]) > thr[2]) ? 1.0f : 0.0f;
    m4[i] = (__float_as_uint(n4[i]) > thr[3]) ? 1.0f : 0.0f;
}

extern "C" void kernel_launch(void* const* d_in, const int* in_sizes, int n_in,
                              void* d_out, int out_size, void* d_ws, size_t ws_size,
                              hipStream_t stream)
{
    const float* x  = (const float*)d_in[0];
    const float* W1 = (const float*)d_in[1];
    const float* b1 = (const float*)d_in[2];
    const float* W2 = (const float*)d_in[3];
    const float* b2 = (const float*)d_in[4];
    const float* W3 = (const float*)d_in[5];
    const float* b3 = (const float*)d_in[6];
    const float* W4 = (const float*)d_in[7];
    const float* b4 = (const float*)d_in[8];

    float* out = (float*)d_out;                 // [65536,10]
    float* m1  = out + (size_t)BATCH * 10;      // [65536] each
    float* m2  = m1 + BATCH;
    float* m3  = m2 + BATCH;
    float* m4  = m3 + BATCH;

    float* ws    = (float*)d_ws;
    float* h1    = ws;                                  // 65536*512
    float* h2    = h1 + (size_t)BATCH * 512;            // 65536*256
    float* h3    = h2 + (size_t)BATCH * 256;            // 65536*10
    float* h4    = h3 + (size_t)BATCH * 10;             // 65536*10
    float* n1    = h4 + (size_t)BATCH * 10;             // 65536 x4
    float* n2    = n1 + BATCH;
    float* n3    = n2 + BATCH;
    float* n4    = n3 + BATCH;
    float* part  = n4 + BATCH;                          // 4*65536
    unsigned* thr = (unsigned*)(part + (size_t)4 * BATCH);  // 4 threshold keys

    // layer 1: x[65536,784] @ W1[784,512]
    gemm_relu_norm<false><<<dim3(256, 4), 256, 0, stream>>>(x, W1, b1, nullptr, nullptr, h1, part, 512, 784);
    reduce_norms_kernel<<<256, 256, 0, stream>>>(part, n1, 4);
    select_kernel<<<1, 1024, 0, stream>>>(n1, thr + 0);

    // layer 2: (h1*m1)[65536,512] @ W2[512,256]  (mask inline from n1/thr1)
    gemm_relu_norm<true><<<dim3(256, 2), 256, 0, stream>>>(h1, W2, b2, n1, thr + 0, h2, part, 256, 512);
    reduce_norms_kernel<<<256, 256, 0, stream>>>(part, n2, 2);
    select_kernel<<<1, 1024, 0, stream>>>(n2, thr + 1);

    // layer 3: (h2*m2)[65536,256] @ W3[256,10]
    layer3_kernel<<<256, 256, 0, stream>>>(h2, W3, b3, n2, thr + 1, h3, n3);
    select_kernel<<<1, 1024, 0, stream>>>(n3, thr + 2);

    // layer 4: (h3*m3)[65536,10] @ W4[10,10] (no relu)
    layer4_kernel<<<256, 256, 0, stream>>>(h3, W4, b4, n3, thr + 2, h4, n4);
    select_kernel<<<1, 1024, 0, stream>>>(n4, thr + 3);

    // softmax(h4*m4)
    softmax_kernel<<<256, 256, 0, stream>>>(h4, n4, thr + 3, out);

    // masks m1..m4 -> d_out
    masks_kernel<<<256, 256, 0, stream>>>(n1, n2, n3, n4, thr, m1, m2, m3, m4);
}